// Round 3
// baseline (896.507 us; speedup 1.0000x reference)
//
#include <hip/hip_runtime.h>
#include <math.h>

#define SCAN_B 512
#define NBSHIFT 8
#define CHUNK 8192

typedef __attribute__((ext_vector_type(8))) short short8;
typedef __attribute__((ext_vector_type(4))) float v4f;

__device__ __forceinline__ unsigned short f2bf(float f) {
    unsigned int u = __float_as_uint(f);
    u += 0x7FFFu + ((u >> 16) & 1u);  // RNE
    return (unsigned short)(u >> 16);
}
__device__ __forceinline__ unsigned int packbf(float a, float b) {
    return (unsigned int)f2bf(a) | ((unsigned int)f2bf(b) << 16);
}
__device__ __forceinline__ void bf8_to_f32(uint4 v, float* f) {
    f[0] = __uint_as_float(v.x << 16); f[1] = __uint_as_float(v.x & 0xFFFF0000u);
    f[2] = __uint_as_float(v.y << 16); f[3] = __uint_as_float(v.y & 0xFFFF0000u);
    f[4] = __uint_as_float(v.z << 16); f[5] = __uint_as_float(v.z & 0xFFFF0000u);
    f[6] = __uint_as_float(v.w << 16); f[7] = __uint_as_float(v.w & 0xFFFF0000u);
}

// ---------------- degree count ----------------
__global__ void count_deg_kernel(const int* __restrict__ dst, int E, int* __restrict__ counts) {
    int e = blockIdx.x * blockDim.x + threadIdx.x;
    if (e < E) atomicAdd(&counts[dst[e]], 1);
}

// ---------------- exclusive scan (3-phase) ----------------
__global__ void scan1_kernel(const int* __restrict__ counts, int N,
                             int* __restrict__ partial, int* __restrict__ blockSums) {
    __shared__ int sm[SCAN_B];
    int tid = threadIdx.x;
    int i = blockIdx.x * SCAN_B + tid;
    int v = (i < N) ? counts[i] : 0;
    sm[tid] = v;
    __syncthreads();
    for (int off = 1; off < SCAN_B; off <<= 1) {
        int t = (tid >= off) ? sm[tid - off] : 0;
        __syncthreads();
        sm[tid] += t;
        __syncthreads();
    }
    if (i < N) partial[i] = sm[tid] - v;
    if (tid == SCAN_B - 1) blockSums[blockIdx.x] = sm[tid];
}

__global__ void scan2_kernel(int* __restrict__ blockSums, int nb) {
    __shared__ int sm[256];
    int tid = threadIdx.x;
    int v = (tid < nb) ? blockSums[tid] : 0;
    sm[tid] = v;
    __syncthreads();
    for (int off = 1; off < 256; off <<= 1) {
        int t = (tid >= off) ? sm[tid - off] : 0;
        __syncthreads();
        sm[tid] += t;
        __syncthreads();
    }
    if (tid < nb) blockSums[tid] = sm[tid] - v;
}

__global__ void scan3_kernel(const int* __restrict__ counts, int* __restrict__ offsets,
                             const int* __restrict__ blockSums, int N, int E,
                             int* __restrict__ cursor, float* __restrict__ dinv) {
    int i = blockIdx.x * SCAN_B + threadIdx.x;
    if (i < N) {
        int off = offsets[i] + blockSums[blockIdx.x];
        offsets[i] = off;
        cursor[i] = off;
        dinv[i] = rsqrtf((float)(counts[i] + 1));
    }
    if (i == 0 && blockIdx.x == 0) offsets[N] = E;
}

// ---------------- bin bases ----------------
__global__ void binbase_kernel(const int* __restrict__ offsets, int* __restrict__ bin_base,
                               int* __restrict__ bin_cursor, int nbins, int N) {
    int b = blockIdx.x * 256 + threadIdx.x;
    if (b <= nbins) {
        int node = b << NBSHIFT;
        if (node > N) node = N;
        bin_base[b] = offsets[node];
        if (b < nbins) bin_cursor[b] = offsets[node];
    }
}

// ---------------- phase B: local counting-sort into coarse bins ----------------
__global__ __launch_bounds__(256) void binpass_kernel(const int* __restrict__ src,
                                                      const int* __restrict__ dst, int E,
                                                      int* __restrict__ bin_cursor,
                                                      unsigned int* __restrict__ bpairs, int nbins) {
    __shared__ unsigned int pk[CHUNK];
    __shared__ unsigned short binOf[CHUNK];
    __shared__ int hist[512];
    __shared__ int scanned[512];
    __shared__ int rank[512];
    __shared__ int gbase[512];
    int tid = threadIdx.x;
    int base = blockIdx.x * CHUNK;
    int cnt = E - base; if (cnt > CHUNK) cnt = CHUNK;

    for (int i = tid; i < 512; i += 256) { hist[i] = 0; rank[i] = 0; }
    __syncthreads();
    for (int i = tid; i < cnt; i += 256) {
        int d = dst[base + i];
        atomicAdd(&hist[d >> NBSHIFT], 1);
    }
    __syncthreads();
    scanned[tid] = hist[tid]; scanned[tid + 256] = hist[tid + 256];
    __syncthreads();
    for (int off = 1; off < 512; off <<= 1) {
        int i0 = tid, i1 = tid + 256;
        int v0 = (i0 >= off) ? scanned[i0 - off] : 0;
        int v1 = (i1 >= off) ? scanned[i1 - off] : 0;
        __syncthreads();
        scanned[i0] += v0; scanned[i1] += v1;
        __syncthreads();
    }
    for (int i = tid; i < cnt; i += 256) {
        int d = dst[base + i];
        int s = src[base + i];
        int b = d >> NBSHIFT;
        unsigned int p = (unsigned int)s | ((unsigned int)(d & 255) << 17);
        int r = atomicAdd(&rank[b], 1);
        int pos = scanned[b] - hist[b] + r;
        pk[pos] = p;
        binOf[pos] = (unsigned short)b;
    }
    __syncthreads();
    for (int b = tid; b < nbins; b += 256)
        if (hist[b] > 0) gbase[b] = atomicAdd(&bin_cursor[b], hist[b]);
    __syncthreads();
    for (int i = tid; i < cnt; i += 256) {
        int b = binOf[i];
        int local = i - (scanned[b] - hist[b]);
        bpairs[gbase[b] + local] = pk[i];
    }
}

// ---------------- phase C: per-bin fine scatter ----------------
__global__ __launch_bounds__(256) void binscatter_kernel(const unsigned int* __restrict__ bpairs,
                                                         const int* __restrict__ bin_base,
                                                         int* __restrict__ cursor,
                                                         int* __restrict__ ssrc) {
    int b = blockIdx.x;
    int start = bin_base[b], end = bin_base[b + 1];
    int dhigh = b << NBSHIFT;
    for (int i = start + threadIdx.x; i < end; i += 256) {
        unsigned int p = bpairs[i];
        int s = (int)(p & 0x1FFFFu);
        int d = dhigh | (int)(p >> 17);
        int pos = atomicAdd(&cursor[d], 1);
        ssrc[pos] = s;
    }
}

// ---------------- W1 cast into pre-swizzled full-row LDS image ----------------
// ushort index = (n*512 + k) ^ ((n&7)<<3)  (XOR spreads rows across 16B bank slots)
__global__ void w1cast_kernel(const float* __restrict__ W1, unsigned short* __restrict__ W1s) {
    int idx = blockIdx.x * 256 + threadIdx.x;  // 0..65535 = k*128 + n
    int k = idx >> 7, n = idx & 127;
    int us = (n * 512 + k) ^ ((n & 7) << 3);
    W1s[us] = f2bf(W1[idx]);
}

// ---------------- GEMM1 v3: whole W in LDS (128 KB), barrier-free K loop ----------------
// 196 blocks x 1024 thr (16 waves); each wave owns 16 rows x 128 cols.
// A: direct global->reg->bf16 (no LDS, no barriers). B: LDS resident, swizzled ds_read_b128.
// Operand-swapped MFMA: D[n][m] with m=lane&15 -> per-lane ushort4 C-stores, no C staging.
__global__ __launch_bounds__(1024, 4) void gemm1_mfma_kernel(const float* __restrict__ X,
                                                             const unsigned short* __restrict__ W1s,
                                                             unsigned short* __restrict__ H,
                                                             int N, int nChunks) {
    extern __shared__ char smem[];  // 128 KB pre-swizzled W image
    unsigned short* Bs = (unsigned short*)smem;
    int tid = threadIdx.x;
    #pragma unroll
    for (int i = 0; i < 8; i++)
        ((uint4*)Bs)[tid + (i << 10)] = ((const uint4*)W1s)[tid + (i << 10)];
    __syncthreads();  // the only block-wide barrier

    int wave = tid >> 6, lane = tid & 63;
    int quad = lane >> 4, lr = lane & 15;
    // swizzled per-lane base pointers; low 7 bits = (kc*64 + quad*16) ^ ((n&7)<<4), n&7 = lr&7
    const char* spRow = smem + lr * 1024;
    const char* sp0 = spRow + ((quad * 16) ^ ((lr & 7) << 4));
    const char* sp1 = spRow + ((quad * 16 + 64) ^ ((lr & 7) << 4));

    for (int c = 0;; c++) {
        int chunk = blockIdx.x + c * gridDim.x;
        if (chunk >= nChunks) break;
        int row = (chunk << 8) + (wave << 4) + lr;
        int rowc = row < N ? row : N - 1;  // OOB rows compute garbage, never stored
        const float* pA = X + (size_t)rowc * 512 + quad * 8;
        float4 pf0 = *(const float4*)(pA);
        float4 pf1 = *(const float4*)(pA + 4);
        float4 pf2 = *(const float4*)(pA + 32);
        float4 pf3 = *(const float4*)(pA + 36);
        v4f acc[8];
        #pragma unroll
        for (int j = 0; j < 8; j++) acc[j] = (v4f){0.f, 0.f, 0.f, 0.f};

        #pragma unroll
        for (int ks = 0; ks < 8; ks++) {
            uint4 ua, ub;
            ua.x = packbf(pf0.x, pf0.y); ua.y = packbf(pf0.z, pf0.w);
            ua.z = packbf(pf1.x, pf1.y); ua.w = packbf(pf1.z, pf1.w);
            ub.x = packbf(pf2.x, pf2.y); ub.y = packbf(pf2.z, pf2.w);
            ub.z = packbf(pf3.x, pf3.y); ub.w = packbf(pf3.z, pf3.w);
            short8 aF0, aF1;
            *(uint4*)&aF0 = ua;
            *(uint4*)&aF1 = ub;
            if (ks < 7) {  // prefetch next k-step; stays in flight under the MFMAs
                int k0 = ks * 64;
                pf0 = *(const float4*)(pA + k0 + 64);
                pf1 = *(const float4*)(pA + k0 + 68);
                pf2 = *(const float4*)(pA + k0 + 96);
                pf3 = *(const float4*)(pA + k0 + 100);
            }
            #pragma unroll
            for (int j = 0; j < 8; j++) {
                short8 bF = *(const short8*)(sp0 + j * 16384 + ks * 128);
                acc[j] = __builtin_amdgcn_mfma_f32_16x16x32_bf16(bF, aF0, acc[j], 0, 0, 0);
            }
            #pragma unroll
            for (int j = 0; j < 8; j++) {
                short8 bF = *(const short8*)(sp1 + j * 16384 + ks * 128);
                acc[j] = __builtin_amdgcn_mfma_f32_16x16x32_bf16(bF, aF1, acc[j], 0, 0, 0);
            }
        }
        if (row < N) {
            unsigned short* pH = H + (size_t)row * 128 + quad * 4;
            #pragma unroll
            for (int j = 0; j < 8; j++) {
                ushort4 o;
                o.x = f2bf(acc[j][0]); o.y = f2bf(acc[j][1]);
                o.z = f2bf(acc[j][2]); o.w = f2bf(acc[j][3]);
                *(ushort4*)(pH + j * 16) = o;
            }
        }
    }
}

// ---------------- Agg1: bf16 gather, 16 lanes/node, f32 accumulate, bf16 out ----------------
__global__ __launch_bounds__(256) void agg1_kernel(const unsigned short* __restrict__ h1,
                                                   const int* __restrict__ offsets,
                                                   const int* __restrict__ ssrc,
                                                   const float* __restrict__ dinv,
                                                   const float* __restrict__ bias,
                                                   unsigned short* __restrict__ a1, int N) {
    int lane = threadIdx.x & 15;
    int node = (blockIdx.x << 4) + (threadIdx.x >> 4);
    if (node >= N) return;
    const uint4* h = (const uint4*)h1;  // row = 16 uint4 (128 bf16)
    float di = dinv[node];
    float acc[8], t[8];
    bf8_to_f32(h[(size_t)node * 16 + lane], t);
    #pragma unroll
    for (int i = 0; i < 8; i++) acc[i] = di * t[i];
    int e = offsets[node], e1 = offsets[node + 1];
    for (; e + 3 < e1; e += 4) {
        int sA = ssrc[e], sB = ssrc[e + 1], sC = ssrc[e + 2], sD = ssrc[e + 3];
        float wA = dinv[sA], wB = dinv[sB], wC = dinv[sC], wD = dinv[sD];
        uint4 vA = h[(size_t)sA * 16 + lane];
        uint4 vB = h[(size_t)sB * 16 + lane];
        uint4 vC = h[(size_t)sC * 16 + lane];
        uint4 vD = h[(size_t)sD * 16 + lane];
        float fA[8], fB[8], fC[8], fD[8];
        bf8_to_f32(vA, fA); bf8_to_f32(vB, fB); bf8_to_f32(vC, fC); bf8_to_f32(vD, fD);
        #pragma unroll
        for (int i = 0; i < 8; i++) {
            acc[i] = fmaf(wA, fA[i], acc[i]);
            acc[i] = fmaf(wB, fB[i], acc[i]);
            acc[i] = fmaf(wC, fC[i], acc[i]);
            acc[i] = fmaf(wD, fD[i], acc[i]);
        }
    }
    for (; e < e1; e++) {
        int s = ssrc[e];
        float w = dinv[s];
        float fs[8];
        bf8_to_f32(h[(size_t)s * 16 + lane], fs);
        #pragma unroll
        for (int i = 0; i < 8; i++) acc[i] = fmaf(w, fs[i], acc[i]);
    }
    float4 b0 = ((const float4*)bias)[lane * 2];
    float4 b1v = ((const float4*)bias)[lane * 2 + 1];
    float bb[8] = {b0.x, b0.y, b0.z, b0.w, b1v.x, b1v.y, b1v.z, b1v.w};
    float o[8];
    #pragma unroll
    for (int i = 0; i < 8; i++) o[i] = fmaxf(fmaf(di, acc[i], bb[i]), 0.f);
    uint4 pv;
    pv.x = packbf(o[0], o[1]); pv.y = packbf(o[2], o[3]);
    pv.z = packbf(o[4], o[5]); pv.w = packbf(o[6], o[7]);
    ((uint4*)a1)[(size_t)node * 16 + lane] = pv;
}

// ---------------- GEMM2: [N,128](bf16) @ [128,40] -> [N,40] f32 ----------------
__global__ __launch_bounds__(256) void gemm2_kernel(const unsigned short* __restrict__ A,
                                                    const float* __restrict__ W,
                                                    float* __restrict__ H, int N) {
    __shared__ float As2[128][64];   // [k][m], 32 KB
    __shared__ float Ws[128 * 40];
    int tid = threadIdx.x;
    int rowBase = blockIdx.x * 64;

    #pragma unroll
    for (int l = 0; l < 4; l++) {
        int e = tid + l * 256;
        int r = e >> 4;            // 16 uint4 per row
        int kk = (e & 15) << 3;    // 8 bf16 per uint4
        int grow = rowBase + r;
        float f[8] = {0.f, 0.f, 0.f, 0.f, 0.f, 0.f, 0.f, 0.f};
        if (grow < N) {
            uint4 v = *(const uint4*)(A + (size_t)grow * 128 + kk);
            bf8_to_f32(v, f);
        }
        #pragma unroll
        for (int q = 0; q < 8; q++) As2[kk + q][r] = f[q];
    }
    #pragma unroll
    for (int l = 0; l < 5; l++) {
        int e = tid + l * 256;
        *(float4*)&Ws[e << 2] = *(const float4*)&W[e << 2];
    }
    __syncthreads();

    int tx = tid & 7;
    int ty = tid >> 3;
    float acc[2][5];
    #pragma unroll
    for (int r = 0; r < 2; r++)
        #pragma unroll
        for (int c = 0; c < 5; c++) acc[r][c] = 0.f;

    #pragma unroll 8
    for (int k = 0; k < 128; k++) {
        float a0 = As2[k][ty * 2];
        float a1v = As2[k][ty * 2 + 1];
        #pragma unroll
        for (int c = 0; c < 5; c++) {
            float w = Ws[k * 40 + tx * 5 + c];
            acc[0][c] = fmaf(a0, w, acc[0][c]);
            acc[1][c] = fmaf(a1v, w, acc[1][c]);
        }
    }
    #pragma unroll
    for (int r = 0; r < 2; r++) {
        int grow = rowBase + ty * 2 + r;
        if (grow < N) {
            #pragma unroll
            for (int c = 0; c < 5; c++) H[grow * 40 + tx * 5 + c] = acc[r][c];
        }
    }
}

// ---------------- Agg2 + bias + log_softmax ----------------
__global__ __launch_bounds__(256) void agg2_kernel(const float* __restrict__ h2,
                                                   const int* __restrict__ offsets,
                                                   const int* __restrict__ ssrc,
                                                   const float* __restrict__ dinv,
                                                   const float* __restrict__ bias,
                                                   float* __restrict__ out, int N) {
    int node = blockIdx.x * 4 + (threadIdx.x >> 6);
    int lane = threadIdx.x & 63;
    if (node >= N) return;
    float di = dinv[node];
    bool act = lane < 40;
    float acc = 0.f;
    if (act) acc = di * h2[(size_t)node * 40 + lane];
    int e = offsets[node], e1 = offsets[node + 1];
    for (; e + 3 < e1; e += 4) {
        int sa = ssrc[e], sb = ssrc[e + 1], sc = ssrc[e + 2], sd = ssrc[e + 3];
        float wa = dinv[sa], wb = dinv[sb], wc = dinv[sc], wd = dinv[sd];
        if (act) {
            float ha = h2[(size_t)sa * 40 + lane];
            float hb = h2[(size_t)sb * 40 + lane];
            float hc = h2[(size_t)sc * 40 + lane];
            float hd = h2[(size_t)sd * 40 + lane];
            acc = fmaf(wa, ha, acc); acc = fmaf(wb, hb, acc);
            acc = fmaf(wc, hc, acc); acc = fmaf(wd, hd, acc);
        }
    }
    for (; e < e1; e++) {
        int s = ssrc[e];
        float w = dinv[s];
        if (act) acc = fmaf(w, h2[(size_t)s * 40 + lane], acc);
    }
    float v = act ? fmaf(di, acc, bias[lane]) : -INFINITY;
    float m = v;
    #pragma unroll
    for (int off = 32; off; off >>= 1) m = fmaxf(m, __shfl_xor(m, off, 64));
    float ex = act ? expf(v - m) : 0.f;
    float s = ex;
    #pragma unroll
    for (int off = 32; off; off >>= 1) s += __shfl_xor(s, off, 64);
    if (act) out[(size_t)node * 40 + lane] = v - m - logf(s);
}

// ---------------- launch ----------------
extern "C" void kernel_launch(void* const* d_in, const int* in_sizes, int n_in,
                              void* d_out, int out_size, void* d_ws, size_t ws_size,
                              hipStream_t stream) {
    const float* x  = (const float*)d_in[0];
    const int*   ei = (const int*)d_in[1];
    const float* W1 = (const float*)d_in[2];
    const float* b1 = (const float*)d_in[3];
    const float* W2 = (const float*)d_in[4];
    const float* b2 = (const float*)d_in[5];
    float* out = (float*)d_out;

    int N = in_sizes[0] / 512;
    int E = in_sizes[1] / 2;
    const int* src = ei;
    const int* dst = ei + E;
    int nbins = (N + 255) >> NBSHIFT;  // 391 (src fits 17 bits: N < 131072)

    char* ws = (char*)d_ws;
    size_t off = 0;
    auto alloc = [&](size_t bytes) -> void* {
        void* p = ws + off;
        off += (bytes + 255) & ~(size_t)255;
        return p;
    };
    int*   counts    = (int*)alloc((size_t)N * 4);
    int*   offsets   = (int*)alloc((size_t)(N + 1) * 4);
    int*   cursor    = (int*)alloc((size_t)N * 4);
    float* dinv      = (float*)alloc((size_t)N * 4);
    int nb = (N + SCAN_B - 1) / SCAN_B;
    int*   blockSums = (int*)alloc((size_t)nb * 4);
    int*   bin_base  = (int*)alloc((size_t)(nbins + 1) * 4);
    int*   bin_cur   = (int*)alloc((size_t)nbins * 4);
    int*   ssrc      = (int*)alloc((size_t)E * 4);
    unsigned short* W1s = (unsigned short*)alloc((size_t)128 * 512 * 2);
    unsigned short* h1  = (unsigned short*)alloc((size_t)N * 128 * 2);
    unsigned short* a1  = (unsigned short*)alloc((size_t)N * 128 * 2);
    float* h2        = (float*)alloc((size_t)N * 40 * 4);
    unsigned int* bpairs = (unsigned int*)h1;  // alias: E*4=6.4MB < 25.6MB, consumed pre-gemm1
    (void)ws_size; (void)n_in; (void)out_size;

    hipMemsetAsync(counts, 0, (size_t)N * 4, stream);
    count_deg_kernel<<<(E + 255) / 256, 256, 0, stream>>>(dst, E, counts);
    scan1_kernel<<<nb, SCAN_B, 0, stream>>>(counts, N, offsets, blockSums);
    scan2_kernel<<<1, 256, 0, stream>>>(blockSums, nb);
    scan3_kernel<<<nb, SCAN_B, 0, stream>>>(counts, offsets, blockSums, N, E, cursor, dinv);
    binbase_kernel<<<(nbins + 256) / 256, 256, 0, stream>>>(offsets, bin_base, bin_cur, nbins, N);
    binpass_kernel<<<(E + CHUNK - 1) / CHUNK, 256, 0, stream>>>(src, dst, E, bin_cur, bpairs, nbins);
    binscatter_kernel<<<nbins, 256, 0, stream>>>(bpairs, bin_base, cursor, ssrc);
    w1cast_kernel<<<256, 256, 0, stream>>>(W1, W1s);
    int nChunks = (N + 255) >> 8;                 // 256 rows per block-chunk
    int g1grid = nChunks < 196 ? nChunks : 196;   // 1 block/CU (128 KB LDS)
    gemm1_mfma_kernel<<<g1grid, 1024, 131072, stream>>>(x, W1s, h1, N, nChunks);
    agg1_kernel<<<(N + 15) / 16, 256, 0, stream>>>(h1, offsets, ssrc, dinv, b1, a1, N);
    gemm2_kernel<<<(N + 63) / 64, 256, 0, stream>>>(a1, W2, h2, N);
    agg2_kernel<<<(N + 3) / 4, 256, 0, stream>>>(h2, offsets, ssrc, dinv, b2, out, N);
}

// Round 4
// 607.304 us; speedup vs baseline: 1.4762x; 1.4762x over previous
//
#include <hip/hip_runtime.h>
#include <math.h>

#define SCAN_B 512
#define NBSHIFT 8
#define CHUNK 8192

typedef __attribute__((ext_vector_type(8))) short short8;
typedef __attribute__((ext_vector_type(4))) float v4f;

__device__ __forceinline__ unsigned short f2bf(float f) {
    unsigned int u = __float_as_uint(f);
    u += 0x7FFFu + ((u >> 16) & 1u);  // RNE
    return (unsigned short)(u >> 16);
}
__device__ __forceinline__ unsigned int packbf(float a, float b) {
    return (unsigned int)f2bf(a) | ((unsigned int)f2bf(b) << 16);
}
__device__ __forceinline__ void bf8_to_f32(uint4 v, float* f) {
    f[0] = __uint_as_float(v.x << 16); f[1] = __uint_as_float(v.x & 0xFFFF0000u);
    f[2] = __uint_as_float(v.y << 16); f[3] = __uint_as_float(v.y & 0xFFFF0000u);
    f[4] = __uint_as_float(v.z << 16); f[5] = __uint_as_float(v.z & 0xFFFF0000u);
    f[6] = __uint_as_float(v.w << 16); f[7] = __uint_as_float(v.w & 0xFFFF0000u);
}

// ---------------- degree count ----------------
__global__ void count_deg_kernel(const int* __restrict__ dst, int E, int* __restrict__ counts) {
    int e = blockIdx.x * blockDim.x + threadIdx.x;
    if (e < E) atomicAdd(&counts[dst[e]], 1);
}

// ---------------- exclusive scan (3-phase) ----------------
__global__ void scan1_kernel(const int* __restrict__ counts, int N,
                             int* __restrict__ partial, int* __restrict__ blockSums) {
    __shared__ int sm[SCAN_B];
    int tid = threadIdx.x;
    int i = blockIdx.x * SCAN_B + tid;
    int v = (i < N) ? counts[i] : 0;
    sm[tid] = v;
    __syncthreads();
    for (int off = 1; off < SCAN_B; off <<= 1) {
        int t = (tid >= off) ? sm[tid - off] : 0;
        __syncthreads();
        sm[tid] += t;
        __syncthreads();
    }
    if (i < N) partial[i] = sm[tid] - v;
    if (tid == SCAN_B - 1) blockSums[blockIdx.x] = sm[tid];
}

__global__ void scan2_kernel(int* __restrict__ blockSums, int nb) {
    __shared__ int sm[256];
    int tid = threadIdx.x;
    int v = (tid < nb) ? blockSums[tid] : 0;
    sm[tid] = v;
    __syncthreads();
    for (int off = 1; off < 256; off <<= 1) {
        int t = (tid >= off) ? sm[tid - off] : 0;
        __syncthreads();
        sm[tid] += t;
        __syncthreads();
    }
    if (tid < nb) blockSums[tid] = sm[tid] - v;
}

__global__ void scan3_kernel(const int* __restrict__ counts, int* __restrict__ offsets,
                             const int* __restrict__ blockSums, int N, int E,
                             int* __restrict__ cursor, float* __restrict__ dinv) {
    int i = blockIdx.x * SCAN_B + threadIdx.x;
    if (i < N) {
        int off = offsets[i] + blockSums[blockIdx.x];
        offsets[i] = off;
        cursor[i] = off;
        dinv[i] = rsqrtf((float)(counts[i] + 1));
    }
    if (i == 0 && blockIdx.x == 0) offsets[N] = E;
}

// ---------------- bin bases ----------------
__global__ void binbase_kernel(const int* __restrict__ offsets, int* __restrict__ bin_base,
                               int* __restrict__ bin_cursor, int nbins, int N) {
    int b = blockIdx.x * 256 + threadIdx.x;
    if (b <= nbins) {
        int node = b << NBSHIFT;
        if (node > N) node = N;
        bin_base[b] = offsets[node];
        if (b < nbins) bin_cursor[b] = offsets[node];
    }
}

// ---------------- phase B: local counting-sort into coarse bins ----------------
__global__ __launch_bounds__(256) void binpass_kernel(const int* __restrict__ src,
                                                      const int* __restrict__ dst, int E,
                                                      int* __restrict__ bin_cursor,
                                                      unsigned int* __restrict__ bpairs, int nbins) {
    __shared__ unsigned int pk[CHUNK];
    __shared__ unsigned short binOf[CHUNK];
    __shared__ int hist[512];
    __shared__ int scanned[512];
    __shared__ int rank[512];
    __shared__ int gbase[512];
    int tid = threadIdx.x;
    int base = blockIdx.x * CHUNK;
    int cnt = E - base; if (cnt > CHUNK) cnt = CHUNK;

    for (int i = tid; i < 512; i += 256) { hist[i] = 0; rank[i] = 0; }
    __syncthreads();
    for (int i = tid; i < cnt; i += 256) {
        int d = dst[base + i];
        atomicAdd(&hist[d >> NBSHIFT], 1);
    }
    __syncthreads();
    scanned[tid] = hist[tid]; scanned[tid + 256] = hist[tid + 256];
    __syncthreads();
    for (int off = 1; off < 512; off <<= 1) {
        int i0 = tid, i1 = tid + 256;
        int v0 = (i0 >= off) ? scanned[i0 - off] : 0;
        int v1 = (i1 >= off) ? scanned[i1 - off] : 0;
        __syncthreads();
        scanned[i0] += v0; scanned[i1] += v1;
        __syncthreads();
    }
    for (int i = tid; i < cnt; i += 256) {
        int d = dst[base + i];
        int s = src[base + i];
        int b = d >> NBSHIFT;
        unsigned int p = (unsigned int)s | ((unsigned int)(d & 255) << 17);
        int r = atomicAdd(&rank[b], 1);
        int pos = scanned[b] - hist[b] + r;
        pk[pos] = p;
        binOf[pos] = (unsigned short)b;
    }
    __syncthreads();
    for (int b = tid; b < nbins; b += 256)
        if (hist[b] > 0) gbase[b] = atomicAdd(&bin_cursor[b], hist[b]);
    __syncthreads();
    for (int i = tid; i < cnt; i += 256) {
        int b = binOf[i];
        int local = i - (scanned[b] - hist[b]);
        bpairs[gbase[b] + local] = pk[i];
    }
}

// ---------------- phase C: per-bin fine scatter ----------------
__global__ __launch_bounds__(256) void binscatter_kernel(const unsigned int* __restrict__ bpairs,
                                                         const int* __restrict__ bin_base,
                                                         int* __restrict__ cursor,
                                                         int* __restrict__ ssrc) {
    int b = blockIdx.x;
    int start = bin_base[b], end = bin_base[b + 1];
    int dhigh = b << NBSHIFT;
    for (int i = start + threadIdx.x; i < end; i += 256) {
        unsigned int p = bpairs[i];
        int s = (int)(p & 0x1FFFFu);
        int d = dhigh | (int)(p >> 17);
        int pos = atomicAdd(&cursor[d], 1);
        ssrc[pos] = s;
    }
}

// ---------------- W1 cast into pre-swizzled LDS-image layout ----------------
// W1s[kb*8192 + n*64 + ((c ^ (n&7))<<3) + h] = bf16(W1[(kb*64 + c*8 + h)*128 + n])
// so a LINEAR 16KB copy of block kb into LDS yields exactly the swizzled B tile.
__global__ void w1cast_kernel(const float* __restrict__ W1, unsigned short* __restrict__ W1s) {
    int idx = blockIdx.x * 256 + threadIdx.x;  // 0..65535 = k*128 + n
    int k = idx >> 7, n = idx & 127;
    int dstIdx = ((k >> 6) << 13) | (n << 6) | ((((k >> 3) & 7) ^ (n & 7)) << 3) | (k & 7);
    W1s[dstIdx] = f2bf(W1[idx]);
}

// ---------------- GEMM1: [N,512]@[512,128], bf16 MFMA, 128x128 tile (r2-verified) ----------------
#define BM1 128
#define BK1 64

__global__ __launch_bounds__(256) void gemm1_mfma_kernel(const float* __restrict__ X,
                                                         const unsigned short* __restrict__ W1s,
                                                         unsigned short* __restrict__ H, int N) {
    __shared__ unsigned short SMEM[16384];  // 32 KB: As[8192] + Bs[8192]; reused as 128x128 C tile
    unsigned short* As = SMEM;
    unsigned short* Bs = SMEM + 8192;
    int tid = threadIdx.x;
    int wave = tid >> 6, lane = tid & 63;
    int quad = lane >> 4, lr = lane & 15;
    int mBase = (wave & 1) * 64, nBase = (wave >> 1) * 64;  // 2x2 wave grid, 64x64 each
    int rowBase = blockIdx.x * BM1;

    v4f zero4 = {0.f, 0.f, 0.f, 0.f};
    v4f acc[4][4];
    #pragma unroll
    for (int i = 0; i < 4; i++)
        #pragma unroll
        for (int j = 0; j < 4; j++) acc[i][j] = zero4;

    float4 pfA0[4], pfA1[4];  // 8 float4 = 128 rows x 64 k f32 tile / 256 thr
    uint4  pfB[4];            // 16 KB pre-swizzled B panel / 256 thr

    #define LOAD_A(K0)                                                                  \
        _Pragma("unroll")                                                               \
        for (int t = 0; t < 4; t++) {                                                   \
            int idx = tid + t * 256;                                                    \
            int r = idx >> 3, c = idx & 7;                                              \
            int gr = rowBase + r;                                                       \
            const float4* p = (const float4*)(X + (size_t)gr * 512 + (K0) + c * 8);     \
            bool ok = gr < N;                                                           \
            pfA0[t] = ok ? p[0] : make_float4(0.f, 0.f, 0.f, 0.f);                      \
            pfA1[t] = ok ? p[1] : make_float4(0.f, 0.f, 0.f, 0.f);                      \
        }
    #define LOAD_B(K0)                                                                  \
        _Pragma("unroll")                                                               \
        for (int t = 0; t < 4; t++)                                                     \
            pfB[t] = *(const uint4*)(W1s + (((K0) >> 6) << 13) + ((tid + t * 256) << 3));

    LOAD_A(0); LOAD_B(0);

    for (int k0 = 0; k0 < 512; k0 += BK1) {
        __syncthreads();  // previous MFMA reads of LDS done
        #pragma unroll
        for (int t = 0; t < 4; t++) {
            int idx = tid + t * 256;
            int r = idx >> 3, c = idx & 7;
            uint4 v;
            v.x = packbf(pfA0[t].x, pfA0[t].y); v.y = packbf(pfA0[t].z, pfA0[t].w);
            v.z = packbf(pfA1[t].x, pfA1[t].y); v.w = packbf(pfA1[t].z, pfA1[t].w);
            *(uint4*)(&As[(r << 6) + ((c ^ (r & 7)) << 3)]) = v;
        }
        #pragma unroll
        for (int t = 0; t < 4; t++)
            *(uint4*)(&Bs[(tid + t * 256) << 3]) = pfB[t];  // linear: W1s is pre-swizzled
        __syncthreads();
        if (k0 + BK1 < 512) { LOAD_A(k0 + BK1); LOAD_B(k0 + BK1); }  // latency hidden under MFMA
        #pragma unroll
        for (int kc = 0; kc < BK1; kc += 32) {
            int cb = kc >> 3;
            short8 aF[4], bF[4];
            #pragma unroll
            for (int i = 0; i < 4; i++) {
                int m = mBase + i * 16 + lr;
                aF[i] = *(const short8*)(&As[m * 64 + (((cb + quad) ^ (m & 7)) << 3)]);
            }
            #pragma unroll
            for (int j = 0; j < 4; j++) {
                int n = nBase + j * 16 + lr;
                bF[j] = *(const short8*)(&Bs[n * 64 + (((cb + quad) ^ (n & 7)) << 3)]);
            }
            #pragma unroll
            for (int i = 0; i < 4; i++)
                #pragma unroll
                for (int j = 0; j < 4; j++)
                    acc[i][j] = __builtin_amdgcn_mfma_f32_16x16x32_bf16(aF[i], bF[j], acc[i][j], 0, 0, 0);
        }
    }
    // ---- epilogue: stage 128x128 bf16 C tile (32 KB) in SMEM, swizzled, then stream out ----
    __syncthreads();
    unsigned short* Cs = SMEM;
    #pragma unroll
    for (int i = 0; i < 4; i++) {
        #pragma unroll
        for (int r = 0; r < 4; r++) {
            int m = mBase + i * 16 + quad * 4 + r;
            #pragma unroll
            for (int j = 0; j < 4; j++)
                Cs[m * 128 + ((nBase + j * 16 + lr) ^ ((m & 7) << 4))] = f2bf(acc[i][j][r]);
        }
    }
    __syncthreads();
    #pragma unroll
    for (int t = 0; t < 8; t++) {
        int idx = tid + t * 256;          // 0..2047
        int row = idx >> 4, c = idx & 15; // 16 uint4 per 128-col row
        int gr = rowBase + row;
        if (gr < N)
            *(uint4*)(H + (size_t)gr * 128 + c * 8) =
                *(const uint4*)(&Cs[row * 128 + ((c * 8) ^ ((row & 8) ? 0 : 0) ^ ((row & 7) << 4))]);
    }
    #undef LOAD_A
    #undef LOAD_B
}

// ---------------- Agg1: bf16 gather, 16 lanes/node, f32 accumulate, bf16 out ----------------
__global__ __launch_bounds__(256) void agg1_kernel(const unsigned short* __restrict__ h1,
                                                   const int* __restrict__ offsets,
                                                   const int* __restrict__ ssrc,
                                                   const float* __restrict__ dinv,
                                                   const float* __restrict__ bias,
                                                   unsigned short* __restrict__ a1, int N) {
    int lane = threadIdx.x & 15;
    int node = (blockIdx.x << 4) + (threadIdx.x >> 4);
    if (node >= N) return;
    const uint4* h = (const uint4*)h1;  // row = 16 uint4 (128 bf16)
    float di = dinv[node];
    float acc[8], t[8];
    bf8_to_f32(h[(size_t)node * 16 + lane], t);
    #pragma unroll
    for (int i = 0; i < 8; i++) acc[i] = di * t[i];
    int e = offsets[node], e1 = offsets[node + 1];
    for (; e + 3 < e1; e += 4) {
        int sA = ssrc[e], sB = ssrc[e + 1], sC = ssrc[e + 2], sD = ssrc[e + 3];
        float wA = dinv[sA], wB = dinv[sB], wC = dinv[sC], wD = dinv[sD];
        uint4 vA = h[(size_t)sA * 16 + lane];
        uint4 vB = h[(size_t)sB * 16 + lane];
        uint4 vC = h[(size_t)sC * 16 + lane];
        uint4 vD = h[(size_t)sD * 16 + lane];
        float fA[8], fB[8], fC[8], fD[8];
        bf8_to_f32(vA, fA); bf8_to_f32(vB, fB); bf8_to_f32(vC, fC); bf8_to_f32(vD, fD);
        #pragma unroll
        for (int i = 0; i < 8; i++) {
            acc[i] = fmaf(wA, fA[i], acc[i]);
            acc[i] = fmaf(wB, fB[i], acc[i]);
            acc[i] = fmaf(wC, fC[i], acc[i]);
            acc[i] = fmaf(wD, fD[i], acc[i]);
        }
    }
    for (; e < e1; e++) {
        int s = ssrc[e];
        float w = dinv[s];
        float fs[8];
        bf8_to_f32(h[(size_t)s * 16 + lane], fs);
        #pragma unroll
        for (int i = 0; i < 8; i++) acc[i] = fmaf(w, fs[i], acc[i]);
    }
    float4 b0 = ((const float4*)bias)[lane * 2];
    float4 b1v = ((const float4*)bias)[lane * 2 + 1];
    float bb[8] = {b0.x, b0.y, b0.z, b0.w, b1v.x, b1v.y, b1v.z, b1v.w};
    float o[8];
    #pragma unroll
    for (int i = 0; i < 8; i++) o[i] = fmaxf(fmaf(di, acc[i], bb[i]), 0.f);
    uint4 pv;
    pv.x = packbf(o[0], o[1]); pv.y = packbf(o[2], o[3]);
    pv.z = packbf(o[4], o[5]); pv.w = packbf(o[6], o[7]);
    ((uint4*)a1)[(size_t)node * 16 + lane] = pv;
}

// ---------------- GEMM2: [N,128](bf16) @ [128,40] -> [N,40] f32 ----------------
__global__ __launch_bounds__(256) void gemm2_kernel(const unsigned short* __restrict__ A,
                                                    const float* __restrict__ W,
                                                    float* __restrict__ H, int N) {
    __shared__ float As2[128][64];   // [k][m], 32 KB
    __shared__ float Ws[128 * 40];
    int tid = threadIdx.x;
    int rowBase = blockIdx.x * 64;

    #pragma unroll
    for (int l = 0; l < 4; l++) {
        int e = tid + l * 256;
        int r = e >> 4;            // 16 uint4 per row
        int kk = (e & 15) << 3;    // 8 bf16 per uint4
        int grow = rowBase + r;
        float f[8] = {0.f, 0.f, 0.f, 0.f, 0.f, 0.f, 0.f, 0.f};
        if (grow < N) {
            uint4 v = *(const uint4*)(A + (size_t)grow * 128 + kk);
            bf8_to_f32(v, f);
        }
        #pragma unroll
        for (int q = 0; q < 8; q++) As2[kk + q][r] = f[q];
    }
    #pragma unroll
    for (int l = 0; l < 5; l++) {
        int e = tid + l * 256;
        *(float4*)&Ws[e << 2] = *(const float4*)&W[e << 2];
    }
    __syncthreads();

    int tx = tid & 7;
    int ty = tid >> 3;
    float acc[2][5];
    #pragma unroll
    for (int r = 0; r < 2; r++)
        #pragma unroll
        for (int c = 0; c < 5; c++) acc[r][c] = 0.f;

    #pragma unroll 8
    for (int k = 0; k < 128; k++) {
        float a0 = As2[k][ty * 2];
        float a1v = As2[k][ty * 2 + 1];
        #pragma unroll
        for (int c = 0; c < 5; c++) {
            float w = Ws[k * 40 + tx * 5 + c];
            acc[0][c] = fmaf(a0, w, acc[0][c]);
            acc[1][c] = fmaf(a1v, w, acc[1][c]);
        }
    }
    #pragma unroll
    for (int r = 0; r < 2; r++) {
        int grow = rowBase + ty * 2 + r;
        if (grow < N) {
            #pragma unroll
            for (int c = 0; c < 5; c++) H[grow * 40 + tx * 5 + c] = acc[r][c];
        }
    }
}

// ---------------- Agg2 + bias + log_softmax: 16 lanes/node, float4 gathers ----------------
__global__ __launch_bounds__(256) void agg2_kernel(const float* __restrict__ h2,
                                                   const int* __restrict__ offsets,
                                                   const int* __restrict__ ssrc,
                                                   const float* __restrict__ dinv,
                                                   const float* __restrict__ bias,
                                                   float* __restrict__ out, int N) {
    int lane = threadIdx.x & 15;
    int node = (blockIdx.x << 4) + (threadIdx.x >> 4);
    if (node >= N) return;
    const float4* h = (const float4*)h2;  // row = 10 float4 (40 f32)
    float di = dinv[node];
    bool act = lane < 10;
    float a0 = 0.f, a1 = 0.f, a2 = 0.f, a3 = 0.f;
    if (act) {
        float4 v = h[(size_t)node * 10 + lane];
        a0 = di * v.x; a1 = di * v.y; a2 = di * v.z; a3 = di * v.w;
    }
    int e = offsets[node], e1 = offsets[node + 1];
    for (; e + 3 < e1; e += 4) {
        int sA = ssrc[e], sB = ssrc[e + 1], sC = ssrc[e + 2], sD = ssrc[e + 3];
        float wA = dinv[sA], wB = dinv[sB], wC = dinv[sC], wD = dinv[sD];
        if (act) {
            float4 vA = h[(size_t)sA * 10 + lane];
            float4 vB = h[(size_t)sB * 10 + lane];
            float4 vC = h[(size_t)sC * 10 + lane];
            float4 vD = h[(size_t)sD * 10 + lane];
            a0 = fmaf(wA, vA.x, a0); a1 = fmaf(wA, vA.y, a1);
            a2 = fmaf(wA, vA.z, a2); a3 = fmaf(wA, vA.w, a3);
            a0 = fmaf(wB, vB.x, a0); a1 = fmaf(wB, vB.y, a1);
            a2 = fmaf(wB, vB.z, a2); a3 = fmaf(wB, vB.w, a3);
            a0 = fmaf(wC, vC.x, a0); a1 = fmaf(wC, vC.y, a1);
            a2 = fmaf(wC, vC.z, a2); a3 = fmaf(wC, vC.w, a3);
            a0 = fmaf(wD, vD.x, a0); a1 = fmaf(wD, vD.y, a1);
            a2 = fmaf(wD, vD.z, a2); a3 = fmaf(wD, vD.w, a3);
        }
    }
    for (; e < e1; e++) {
        int s = ssrc[e];
        float w = dinv[s];
        if (act) {
            float4 v = h[(size_t)s * 10 + lane];
            a0 = fmaf(w, v.x, a0); a1 = fmaf(w, v.y, a1);
            a2 = fmaf(w, v.z, a2); a3 = fmaf(w, v.w, a3);
        }
    }
    float v0 = -INFINITY, v1 = -INFINITY, v2 = -INFINITY, v3 = -INFINITY;
    if (act) {
        float4 bb = ((const float4*)bias)[lane];
        v0 = fmaf(di, a0, bb.x); v1 = fmaf(di, a1, bb.y);
        v2 = fmaf(di, a2, bb.z); v3 = fmaf(di, a3, bb.w);
    }
    float m = fmaxf(fmaxf(v0, v1), fmaxf(v2, v3));
    #pragma unroll
    for (int off = 8; off; off >>= 1) m = fmaxf(m, __shfl_xor(m, off, 16));
    float s = act ? (expf(v0 - m) + expf(v1 - m) + expf(v2 - m) + expf(v3 - m)) : 0.f;
    #pragma unroll
    for (int off = 8; off; off >>= 1) s += __shfl_xor(s, off, 16);
    if (act) {
        float ls = logf(s);
        float4 o;
        o.x = v0 - m - ls; o.y = v1 - m - ls; o.z = v2 - m - ls; o.w = v3 - m - ls;
        ((float4*)out)[(size_t)node * 10 + lane] = o;
    }
}

// ---------------- launch ----------------
extern "C" void kernel_launch(void* const* d_in, const int* in_sizes, int n_in,
                              void* d_out, int out_size, void* d_ws, size_t ws_size,
                              hipStream_t stream) {
    const float* x  = (const float*)d_in[0];
    const int*   ei = (const int*)d_in[1];
    const float* W1 = (const float*)d_in[2];
    const float* b1 = (const float*)d_in[3];
    const float* W2 = (const float*)d_in[4];
    const float* b2 = (const float*)d_in[5];
    float* out = (float*)d_out;

    int N = in_sizes[0] / 512;
    int E = in_sizes[1] / 2;
    const int* src = ei;
    const int* dst = ei + E;
    int nbins = (N + 255) >> NBSHIFT;  // 391 (src fits 17 bits: N < 131072)

    char* ws = (char*)d_ws;
    size_t off = 0;
    auto alloc = [&](size_t bytes) -> void* {
        void* p = ws + off;
        off += (bytes + 255) & ~(size_t)255;
        return p;
    };
    int*   counts    = (int*)alloc((size_t)N * 4);
    int*   offsets   = (int*)alloc((size_t)(N + 1) * 4);
    int*   cursor    = (int*)alloc((size_t)N * 4);
    float* dinv      = (float*)alloc((size_t)N * 4);
    int nb = (N + SCAN_B - 1) / SCAN_B;
    int*   blockSums = (int*)alloc((size_t)nb * 4);
    int*   bin_base  = (int*)alloc((size_t)(nbins + 1) * 4);
    int*   bin_cur   = (int*)alloc((size_t)nbins * 4);
    int*   ssrc      = (int*)alloc((size_t)E * 4);
    unsigned short* W1s = (unsigned short*)alloc((size_t)128 * 512 * 2);
    unsigned short* h1  = (unsigned short*)alloc((size_t)N * 128 * 2);
    unsigned short* a1  = (unsigned short*)alloc((size_t)N * 128 * 2);
    float* h2        = (float*)alloc((size_t)N * 40 * 4);
    unsigned int* bpairs = (unsigned int*)h1;  // alias: E*4=6.4MB < 25.6MB, consumed pre-gemm1
    (void)ws_size; (void)n_in; (void)out_size;

    hipMemsetAsync(counts, 0, (size_t)N * 4, stream);
    count_deg_kernel<<<(E + 255) / 256, 256, 0, stream>>>(dst, E, counts);
    scan1_kernel<<<nb, SCAN_B, 0, stream>>>(counts, N, offsets, blockSums);
    scan2_kernel<<<1, 256, 0, stream>>>(blockSums, nb);
    scan3_kernel<<<nb, SCAN_B, 0, stream>>>(counts, offsets, blockSums, N, E, cursor, dinv);
    binbase_kernel<<<(nbins + 256) / 256, 256, 0, stream>>>(offsets, bin_base, bin_cur, nbins, N);
    binpass_kernel<<<(E + CHUNK - 1) / CHUNK, 256, 0, stream>>>(src, dst, E, bin_cur, bpairs, nbins);
    binscatter_kernel<<<nbins, 256, 0, stream>>>(bpairs, bin_base, cursor, ssrc);
    w1cast_kernel<<<256, 256, 0, stream>>>(W1, W1s);
    gemm1_mfma_kernel<<<(N + BM1 - 1) / BM1, 256, 0, stream>>>(x, W1s, h1, N);
    agg1_kernel<<<(N + 15) / 16, 256, 0, stream>>>(h1, offsets, ssrc, dinv, b1, a1, N);
    gemm2_kernel<<<(N + 63) / 64, 256, 0, stream>>>(a1, W2, h2, N);
    agg2_kernel<<<(N + 15) / 16, 256, 0, stream>>>(h2, offsets, ssrc, dinv, b2, out, N);
}